// Round 6
// baseline (7692.626 us; speedup 1.0000x reference)
//
#include <hip/hip_runtime.h>
#include <stdint.h>

#define MB 16    // batch rows per group
#define GW 8     // workgroups per group
#define NU 64    // hidden units per WG (4 waves x 16)
#define HD 512
#define SEQ 512
#define DX 40
#define NPROD 32 // producer waves per group (GW*4)

using short8 = __attribute__((ext_vector_type(8))) short;
using f32x4  = __attribute__((ext_vector_type(4))) float;
typedef unsigned long long ull;

__device__ __forceinline__ unsigned short f2bf(float f) {
  uint32_t u = __builtin_bit_cast(uint32_t, f);
  u += 0x7fffu + ((u >> 16) & 1u);
  return (unsigned short)(u >> 16);
}
__device__ __forceinline__ float sigm(float x) { return 1.0f / (1.0f + __expf(-x)); }
__device__ __forceinline__ ull pack4bf(float4 v) {
  return (ull)f2bf(v.x) | ((ull)f2bf(v.y) << 16) | ((ull)f2bf(v.z) << 32) |
         ((ull)f2bf(v.w) << 48);
}
#define MFMA(a, b, c) __builtin_amdgcn_mfma_f32_16x16x32_bf16((a), (b), (c), 0, 0, 0)

// Protocol: one wave owns 16 units and ALL gates for them (in-register combine).
// h exchange [b][u] bf16 via 2B agent write-through stores; per-wave flag stored
// (relaxed) after an explicit s_waitcnt vmcnt(0) = release. Consumers: each
// staging thread polls exactly its producer's flag, then loads its 64B chunk.
// ONE __syncthreads per step; LDS tiles double-buffered by step parity.

// ---------------- GRU persistent kernel ----------------
__global__ __launch_bounds__(256, 1) void gru_kernel(
    const float* __restrict__ x, const float* __restrict__ Wih,
    const float* __restrict__ Whh, const float* __restrict__ bih,
    const float* __restrict__ bhh, unsigned* __restrict__ flags,
    unsigned short* __restrict__ hbuf, float* __restrict__ o1,
    float* __restrict__ stats)
{
  const int wg = blockIdx.x & (GW - 1);
  const int g  = blockIdx.x >> 3;
  const int tid = threadIdx.x;
  const int wave = tid >> 6;
  const int lane = tid & 63;
  const int n = lane & 15;            // unit within wave tile / A batch row
  const int q = lane >> 4;            // quad
  const int kq = q * 8;
  const int u = wg * NU + wave * 16 + n;  // this lane's unit
  const int bg = g * MB;

  __shared__ unsigned short h_s[2][MB][520];
  __shared__ unsigned short x_s[2][MB][72];  // 0..39 x, 40..63 zero

  for (int i = tid; i < 2 * MB * 24; i += 256) {
    int pbuf = i / (MB * 24), r = (i / 24) % MB, c = 40 + (i % 24);
    x_s[pbuf][r][c] = 0;
  }

  // weight fragments, all 3 gates for this lane's units. B[k][n]: n=lane&15,
  // k=(lane>>4)*8+j.
  short8 WR[16], WZ[16], WN[16], XR[2], XZ[2], XN[2];
  for (int kt = 0; kt < 16; ++kt) {
    const float* pr = Whh + (size_t)(0 * HD + u) * HD + kt * 32 + kq;
    const float* pz = Whh + (size_t)(1 * HD + u) * HD + kt * 32 + kq;
    const float* pn = Whh + (size_t)(2 * HD + u) * HD + kt * 32 + kq;
    short8 fr, fz, fn;
#pragma unroll
    for (int j = 0; j < 8; ++j) {
      fr[j] = (short)f2bf(pr[j]); fz[j] = (short)f2bf(pz[j]);
      fn[j] = (short)f2bf(pn[j]);
    }
    WR[kt] = fr; WZ[kt] = fz; WN[kt] = fn;
  }
  for (int kt = 0; kt < 2; ++kt) {
    short8 fr, fz, fn;
#pragma unroll
    for (int j = 0; j < 8; ++j) {
      int c = kt * 32 + kq + j;
      float vr = (c < DX) ? Wih[(size_t)(0 * HD + u) * DX + c] : 0.0f;
      float vz = (c < DX) ? Wih[(size_t)(1 * HD + u) * DX + c] : 0.0f;
      float vn = (c < DX) ? Wih[(size_t)(2 * HD + u) * DX + c] : 0.0f;
      fr[j] = (short)f2bf(vr); fz[j] = (short)f2bf(vz); fn[j] = (short)f2bf(vn);
    }
    XR[kt] = fr; XZ[kt] = fz; XN[kt] = fn;
  }

  const float b_r  = bih[u] + bhh[u];
  const float b_z  = bih[HD + u] + bhh[HD + u];
  const float b_in = bih[2 * HD + u];
  const float b_hn = bhh[2 * HD + u];

  float hprev[4] = {0.f, 0.f, 0.f, 0.f};
  float ssum = 0.f, ssq = 0.f;

  unsigned* gflags   = flags + g * NPROD * 16;
  unsigned* myflag   = gflags + (wg * 4 + wave) * 16;
  unsigned* pollflag = gflags + (tid >> 3) * 16;
  const int sp = tid >> 3;   // staging producer 0..31
  const int sj = tid & 7;    // rows 2sj, 2sj+1 of that producer's 16-unit slice

  for (int t = 0; t < SEQ; ++t) {
    const int pb = t & 1;
    const ull* hin = (const ull*)(hbuf + ((size_t)g * 2 + pb) * MB * HD);
    unsigned short* hout = hbuf + ((size_t)g * 2 + (pb ^ 1)) * MB * HD;

    while (__hip_atomic_load(pollflag, __ATOMIC_RELAXED,
                             __HIP_MEMORY_SCOPE_AGENT) < (unsigned)t)
      __builtin_amdgcn_s_sleep(1);
    ull w[8];
#pragma unroll
    for (int r2 = 0; r2 < 2; ++r2)
#pragma unroll
      for (int c4 = 0; c4 < 4; ++c4)
        w[r2 * 4 + c4] = __hip_atomic_load(
            hin + (2 * sj + r2) * 128 + sp * 4 + c4, __ATOMIC_RELAXED,
            __HIP_MEMORY_SCOPE_AGENT);
#pragma unroll
    for (int r2 = 0; r2 < 2; ++r2)
#pragma unroll
      for (int c4 = 0; c4 < 4; ++c4)
        *(ull*)(&h_s[pb][2 * sj + r2][sp * 16 + c4 * 4]) = w[r2 * 4 + c4];
    {  // stage x_t: thread (b = tid>>4, c = tid&15), c<10 handles 4 floats
      int b = tid >> 4, c = tid & 15;
      if (c < 10) {
        float4 v = *(const float4*)(x + ((size_t)(bg + b) * SEQ + t) * DX + c * 4);
        *(ull*)(&x_s[pb][b][c * 4]) = pack4bf(v);
      }
    }
    __syncthreads();  // the ONLY barrier per step

    f32x4 aR = {0,0,0,0}, aZ = {0,0,0,0}, aN = {0,0,0,0}, aX = {0,0,0,0};
#pragma unroll
    for (int kt = 0; kt < 16; ++kt) {
      short8 a = *(const short8*)(&h_s[pb][n][kt * 32 + kq]);
      aR = MFMA(a, WR[kt], aR);
      aZ = MFMA(a, WZ[kt], aZ);
      aN = MFMA(a, WN[kt], aN);
    }
    {
      short8 a0 = *(const short8*)(&x_s[pb][n][kq]);
      short8 a1 = *(const short8*)(&x_s[pb][n][32 + kq]);
      aR = MFMA(a0, XR[0], aR); aR = MFMA(a1, XR[1], aR);
      aZ = MFMA(a0, XZ[0], aZ); aZ = MFMA(a1, XZ[1], aZ);
      aX = MFMA(a0, XN[0], aX); aX = MFMA(a1, XN[1], aX);
    }

    float hv[4];
#pragma unroll
    for (int r = 0; r < 4; ++r) {   // C/D: col=lane&15=unit, row=q*4+r=batch
      float rr = sigm(aR[r] + b_r);
      float zz = sigm(aZ[r] + b_z);
      float nn = tanhf(aX[r] + b_in + rr * (aN[r] + b_hn));
      float h = (1.0f - zz) * nn + zz * hprev[r];
      hprev[r] = h; hv[r] = h;
      ssum += h; ssq += h * h;
    }
#pragma unroll
    for (int r = 0; r < 4; ++r)
      __hip_atomic_store(hout + (q * 4 + r) * HD + u, f2bf(hv[r]),
                         __ATOMIC_RELAXED, __HIP_MEMORY_SCOPE_AGENT);
    asm volatile("s_waitcnt vmcnt(0)" ::: "memory");  // wave's stores at LLC
    if (lane == 0)
      __hip_atomic_store(myflag, (unsigned)(t + 1), __ATOMIC_RELAXED,
                         __HIP_MEMORY_SCOPE_AGENT);
#pragma unroll
    for (int r = 0; r < 4; ++r)     // o1 after publish
      o1[((size_t)(bg + q * 4 + r) * SEQ + t) * HD + u] = hv[r];
  }

  atomicAdd(&stats[u], ssum);
  atomicAdd(&stats[HD + u], ssq);
}

// ---------------- LSTM persistent kernel ----------------
__global__ __launch_bounds__(256, 1) void lstm_kernel(
    const float* __restrict__ x, const float* __restrict__ Wih,
    const float* __restrict__ Whh, const float* __restrict__ bih,
    const float* __restrict__ bhh, const float* __restrict__ ssr,
    unsigned* __restrict__ flags, unsigned short* __restrict__ hbuf,
    float* __restrict__ o2)
{
  const int wg = blockIdx.x & (GW - 1);
  const int g  = blockIdx.x >> 3;
  const int tid = threadIdx.x;
  const int wave = tid >> 6;
  const int lane = tid & 63;
  const int n = lane & 15;
  const int q = lane >> 4;
  const int kq = q * 8;
  const int u = wg * NU + wave * 16 + n;
  const int bg = g * MB;

  __shared__ unsigned short h_s[2][MB][520];
  __shared__ unsigned short x_s[2][MB][72];  // 0..39 x, 40 ssr, 41..63 zero

  for (int i = tid; i < 2 * MB * 23; i += 256) {
    int pbuf = i / (MB * 23), r = (i / 23) % MB, c = 41 + (i % 23);
    x_s[pbuf][r][c] = 0;
  }

  short8 WI[16], WF[16], WG_[16], WO[16], XI[2], XF[2], XG[2], XO[2];
  for (int kt = 0; kt < 16; ++kt) {
    const float* pi = Whh + (size_t)(0 * HD + u) * HD + kt * 32 + kq;
    const float* pf = Whh + (size_t)(1 * HD + u) * HD + kt * 32 + kq;
    const float* pg = Whh + (size_t)(2 * HD + u) * HD + kt * 32 + kq;
    const float* po = Whh + (size_t)(3 * HD + u) * HD + kt * 32 + kq;
    short8 fi, ff, fg, fo;
#pragma unroll
    for (int j = 0; j < 8; ++j) {
      fi[j] = (short)f2bf(pi[j]); ff[j] = (short)f2bf(pf[j]);
      fg[j] = (short)f2bf(pg[j]); fo[j] = (short)f2bf(po[j]);
    }
    WI[kt] = fi; WF[kt] = ff; WG_[kt] = fg; WO[kt] = fo;
  }
  for (int kt = 0; kt < 2; ++kt) {
    short8 fi, ff, fg, fo;
#pragma unroll
    for (int j = 0; j < 8; ++j) {
      int c = kt * 32 + kq + j;  // Wih has 41 cols (x 0..39, ssr 40)
      float vi = (c < 41) ? Wih[(size_t)(0 * HD + u) * 41 + c] : 0.0f;
      float vf = (c < 41) ? Wih[(size_t)(1 * HD + u) * 41 + c] : 0.0f;
      float vg = (c < 41) ? Wih[(size_t)(2 * HD + u) * 41 + c] : 0.0f;
      float vo = (c < 41) ? Wih[(size_t)(3 * HD + u) * 41 + c] : 0.0f;
      fi[j] = (short)f2bf(vi); ff[j] = (short)f2bf(vf);
      fg[j] = (short)f2bf(vg); fo[j] = (short)f2bf(vo);
    }
    XI[kt] = fi; XF[kt] = ff; XG[kt] = fg; XO[kt] = fo;
  }

  const float b_i = bih[u] + bhh[u];
  const float b_f = bih[HD + u] + bhh[HD + u];
  const float b_g = bih[2 * HD + u] + bhh[2 * HD + u];
  const float b_o = bih[3 * HD + u] + bhh[3 * HD + u];

  float creg[4] = {0.f, 0.f, 0.f, 0.f};

  unsigned* gflags   = flags + g * NPROD * 16;
  unsigned* myflag   = gflags + (wg * 4 + wave) * 16;
  unsigned* pollflag = gflags + (tid >> 3) * 16;
  const int sp = tid >> 3;
  const int sj = tid & 7;

  for (int t = 0; t < SEQ; ++t) {
    const int pb = t & 1;
    const ull* hin = (const ull*)(hbuf + ((size_t)g * 2 + pb) * MB * HD);
    unsigned short* hout = hbuf + ((size_t)g * 2 + (pb ^ 1)) * MB * HD;

    while (__hip_atomic_load(pollflag, __ATOMIC_RELAXED,
                             __HIP_MEMORY_SCOPE_AGENT) < (unsigned)t)
      __builtin_amdgcn_s_sleep(1);
    ull w[8];
#pragma unroll
    for (int r2 = 0; r2 < 2; ++r2)
#pragma unroll
      for (int c4 = 0; c4 < 4; ++c4)
        w[r2 * 4 + c4] = __hip_atomic_load(
            hin + (2 * sj + r2) * 128 + sp * 4 + c4, __ATOMIC_RELAXED,
            __HIP_MEMORY_SCOPE_AGENT);
#pragma unroll
    for (int r2 = 0; r2 < 2; ++r2)
#pragma unroll
      for (int c4 = 0; c4 < 4; ++c4)
        *(ull*)(&h_s[pb][2 * sj + r2][sp * 16 + c4 * 4]) = w[r2 * 4 + c4];
    {
      int b = tid >> 4, c = tid & 15;
      if (c < 10) {
        float4 v = *(const float4*)(x + ((size_t)(bg + b) * SEQ + t) * DX + c * 4);
        *(ull*)(&x_s[pb][b][c * 4]) = pack4bf(v);
      } else if (c == 10) {
        x_s[pb][b][40] = f2bf(ssr[(size_t)(bg + b) * SEQ + t]);
      }
    }
    __syncthreads();

    f32x4 aI = {0,0,0,0}, aF = {0,0,0,0}, aG = {0,0,0,0}, aO = {0,0,0,0};
#pragma unroll
    for (int kt = 0; kt < 16; ++kt) {
      short8 a = *(const short8*)(&h_s[pb][n][kt * 32 + kq]);
      aI = MFMA(a, WI[kt], aI);
      aF = MFMA(a, WF[kt], aF);
      aG = MFMA(a, WG_[kt], aG);
      aO = MFMA(a, WO[kt], aO);
    }
    {
      short8 a0 = *(const short8*)(&x_s[pb][n][kq]);
      short8 a1 = *(const short8*)(&x_s[pb][n][32 + kq]);
      aI = MFMA(a0, XI[0], aI); aI = MFMA(a1, XI[1], aI);
      aF = MFMA(a0, XF[0], aF); aF = MFMA(a1, XF[1], aF);
      aG = MFMA(a0, XG[0], aG); aG = MFMA(a1, XG[1], aG);
      aO = MFMA(a0, XO[0], aO); aO = MFMA(a1, XO[1], aO);
    }

    float hv[4];
#pragma unroll
    for (int r = 0; r < 4; ++r) {
      float gi = sigm(aI[r] + b_i);
      float gf = sigm(aF[r] + b_f);
      float gg = tanhf(aG[r] + b_g);
      float go = sigm(aO[r] + b_o);
      float c = gf * creg[r] + gi * gg;
      creg[r] = c;
      hv[r] = go * tanhf(c);
    }
#pragma unroll
    for (int r = 0; r < 4; ++r)
      __hip_atomic_store(hout + (q * 4 + r) * HD + u, f2bf(hv[r]),
                         __ATOMIC_RELAXED, __HIP_MEMORY_SCOPE_AGENT);
    asm volatile("s_waitcnt vmcnt(0)" ::: "memory");
    if (lane == 0)
      __hip_atomic_store(myflag, (unsigned)(t + 1), __ATOMIC_RELAXED,
                         __HIP_MEMORY_SCOPE_AGENT);
#pragma unroll
    for (int r = 0; r < 4; ++r)
      o2[((size_t)(bg + q * 4 + r) * SEQ + t) * HD + u] = hv[r];
  }
}

// ---------------- BN-coefficient kernel (1 block) ----------------
__global__ __launch_bounds__(512) void coef_kernel(
    const float* __restrict__ stats, const float* __restrict__ fc1_w,
    const float* __restrict__ fc1_b, const float* __restrict__ fc2_w,
    const float* __restrict__ fc2_b, const float* __restrict__ gamma,
    const float* __restrict__ beta, float* __restrict__ coef)
{
  __shared__ float r1[512], r2[512];
  const int j = threadIdx.x;
  const float inv_n = 1.0f / 32768.0f;
  float mean = stats[j] * inv_n;
  float var = stats[HD + j] * inv_n - mean * mean;
  float scale = gamma[j] * rsqrtf(var + 1e-5f);
  float shift = beta[j] - mean * scale;
  coef[j] = fc1_w[j] * scale;
  coef[HD + j] = fc2_w[j] * scale;
  r1[j] = fc1_w[j] * shift;
  r2[j] = fc2_w[j] * shift;
  __syncthreads();
  for (int s = 256; s > 0; s >>= 1) {
    if (j < s) { r1[j] += r1[j + s]; r2[j] += r2[j + s]; }
    __syncthreads();
  }
  if (j == 0) {
    coef[2 * HD] = r1[0] + fc1_b[0];
    coef[2 * HD + 1] = r2[0] + fc2_b[0];
  }
}

// ---------------- ssr kernel: one wave per (b,t) row ----------------
__global__ __launch_bounds__(256) void ssr_kernel(
    const float* __restrict__ o1, const float* __restrict__ coef,
    float* __restrict__ ssr_ws, float* __restrict__ dssr)
{
  const int row = blockIdx.x * 4 + (threadIdx.x >> 6);
  const int lane = threadIdx.x & 63;
  const float* p = o1 + (size_t)row * HD + lane * 8;
  float s1 = 0.f, s2 = 0.f;
#pragma unroll
  for (int j = 0; j < 8; ++j) {
    float v = p[j];
    s1 += v * coef[lane * 8 + j];
    s2 += v * coef[HD + lane * 8 + j];
  }
#pragma unroll
  for (int off = 32; off > 0; off >>= 1) {
    s1 += __shfl_down(s1, off);
    s2 += __shfl_down(s2, off);
  }
  if (lane == 0) {
    float sr = fmaxf(s1 + coef[2 * HD], 0.0f);
    float w = fabsf(sigm(s2 + coef[2 * HD + 1]));
    float v = sr * (1.0f + w);
    ssr_ws[row] = v;
    dssr[row] = v;
  }
}

// ---------------- fc3 output kernel ----------------
__global__ __launch_bounds__(256) void out_kernel(
    const float* __restrict__ o2, const float* __restrict__ fc3_w,
    const float* __restrict__ fc3_b, float* __restrict__ dout)
{
  const int row = blockIdx.x * 4 + (threadIdx.x >> 6);
  const int lane = threadIdx.x & 63;
  const float* p = o2 + (size_t)row * HD + lane * 8;
  float s = 0.f;
#pragma unroll
  for (int j = 0; j < 8; ++j) s += p[j] * fc3_w[lane * 8 + j];
#pragma unroll
  for (int off = 32; off > 0; off >>= 1) s += __shfl_down(s, off);
  if (lane == 0) dout[row] = fmaxf(s + fc3_b[0], 0.0f);
}

extern "C" void kernel_launch(void* const* d_in, const int* in_sizes, int n_in,
                              void* d_out, int out_size, void* d_ws, size_t ws_size,
                              hipStream_t stream) {
  (void)in_sizes; (void)n_in; (void)out_size; (void)ws_size;
  const float* x    = (const float*)d_in[0];
  const float* gWih = (const float*)d_in[1];
  const float* gWhh = (const float*)d_in[2];
  const float* gbih = (const float*)d_in[3];
  const float* gbhh = (const float*)d_in[4];
  const float* lWih = (const float*)d_in[5];
  const float* lWhh = (const float*)d_in[6];
  const float* lbih = (const float*)d_in[7];
  const float* lbhh = (const float*)d_in[8];
  const float* fc1w = (const float*)d_in[9];
  const float* fc1b = (const float*)d_in[10];
  const float* fc2w = (const float*)d_in[11];
  const float* fc2b = (const float*)d_in[12];
  const float* fc3w = (const float*)d_in[13];
  const float* fc3b = (const float*)d_in[14];
  const float* gam  = (const float*)d_in[15];
  const float* bet  = (const float*)d_in[16];
  float* out = (float*)d_out;

  char* ws = (char*)d_ws;
  unsigned* flags_g = (unsigned*)(ws + 0);            // 4 groups x 32 prod x 64B
  unsigned* flags_l = (unsigned*)(ws + 8192);
  float* stats      = (float*)(ws + 16384);           // 1024 f32
  float* coef       = (float*)(ws + 24576);           // 1026 f32
  float* ssr_ws     = (float*)(ws + 32768);           // 32768 f32
  unsigned short* hbuf_g = (unsigned short*)(ws + 262144);   // 128KB
  unsigned short* hbuf_l = (unsigned short*)(ws + 393216);   // 128KB
  float* o1 = (float*)(ws + 1048576);                 // 64MB
  float* o2 = o1 + (size_t)64 * SEQ * HD;             // 64MB

  hipMemsetAsync(ws, 0, 20480, stream);               // flags + stats
  hipMemsetAsync(ws + 262144, 0, 262144, stream);     // h exchange (h0=0)

  gru_kernel<<<dim3(32), dim3(256), 0, stream>>>(x, gWih, gWhh, gbih, gbhh,
                                                 flags_g, hbuf_g, o1, stats);
  coef_kernel<<<dim3(1), dim3(512), 0, stream>>>(stats, fc1w, fc1b, fc2w, fc2b,
                                                 gam, bet, coef);
  ssr_kernel<<<dim3(8192), dim3(256), 0, stream>>>(o1, coef, ssr_ws, out + 32768);
  lstm_kernel<<<dim3(32), dim3(256), 0, stream>>>(x, lWih, lWhh, lbih, lbhh, ssr_ws,
                                                  flags_l, hbuf_l, o2);
  out_kernel<<<dim3(8192), dim3(256), 0, stream>>>(o2, fc3w, fc3b, out);
}

// Round 8
// 3314.516 us; speedup vs baseline: 2.3209x; 2.3209x over previous
//
#include <hip/hip_runtime.h>
#include <stdint.h>

#define MB 16   // batch rows per group
#define GW 16   // workgroups per group
#define NU 32   // hidden units per WG
#define HD 512
#define SEQ 512
#define DX 40

using short8 = __attribute__((ext_vector_type(8))) short;
using f32x4  = __attribute__((ext_vector_type(4))) float;
typedef unsigned long long ull;

__device__ __forceinline__ unsigned short f2bf(float f) {
  uint32_t u = __builtin_bit_cast(uint32_t, f);
  u += 0x7fffu + ((u >> 16) & 1u);
  return (unsigned short)(u >> 16);
}
__device__ __forceinline__ float sigm(float x) { return 1.0f / (1.0f + __expf(-x)); }

// Protocol (R5-proven primitives only):
//  - h pairs: bf16x2 in 4B words, __hip_atomic_store relaxed AGENT (write-through
//    to LLC). Release = per-WAVE: wave drains its own stores with
//    s_waitcnt vmcnt(0) (R6-proven asm), lane0 stores flag (wg*8+wave).
//  - Consumer staging thread (row sb=tid>>5, colblk cb=tid&31) reads 32B from
//    exactly one producer (wg=cb>>1, wave=sb>>1): polls that flag, then loads.
//  - 2 barriers/step: syncB (stage->MFMA-read, also orders gate_s reuse),
//    syncC (MFMA h_s reads -> next stage, also gates combine).

// ---------------- GRU persistent kernel ----------------
// grid = 64 (4 groups x 16 WGs), 512 threads. Waves 0..5: MFMA (r,z,n x 2 unit
// tiles; n-gate x-fragments zero). Waves 6,7: xn = x @ Wn^T via 2 MFMAs
// (separate because n = tanh(xn + r*hn)). All 8 waves produce 2 h rows each.
__global__ __launch_bounds__(512, 2) void gru_kernel(
    const float* __restrict__ x, const float* __restrict__ Wih,
    const float* __restrict__ Whh, const float* __restrict__ bih,
    const float* __restrict__ bhh, unsigned* __restrict__ flags,
    unsigned short* __restrict__ hbuf, float* __restrict__ o1,
    float* __restrict__ stats)
{
  const int wg = blockIdx.x & (GW - 1);
  const int g  = blockIdx.x >> 4;
  const int tid = threadIdx.x;
  const int wave = tid >> 6;
  const int lane = tid & 63;
  const int u0 = wg * NU;
  const int bg = g * MB;

  __shared__ __attribute__((aligned(16))) unsigned short h_s[MB][520];
  __shared__ __attribute__((aligned(16))) unsigned short x_s[MB][72];
  __shared__ float gate_s[3][MB][NU];
  __shared__ float xn_s[MB][NU];

  for (int i = tid; i < MB * 32; i += 512) x_s[i >> 5][40 + (i & 31)] = 0;

  // weight B-fragments in registers. B[k][n]: n=lane&15, k=(lane>>4)*8+j.
  short8 bfrag[18];
  const int myGate = wave >> 1;
  const int ut = wave & 1;
  const int kq = (lane >> 4) * 8;
  if (wave < 6) {
    const int row = myGate * HD + u0 + ut * 16 + (lane & 15);
    for (int kt = 0; kt < 16; ++kt) {
      const float* p = Whh + (size_t)row * HD + kt * 32 + kq;
      short8 f;
#pragma unroll
      for (int j = 0; j < 8; ++j) f[j] = (short)f2bf(p[j]);
      bfrag[kt] = f;
    }
    for (int kt = 16; kt < 18; ++kt) {   // x cols: r,z only (n via xn MFMA)
      short8 f;
#pragma unroll
      for (int j = 0; j < 8; ++j) {
        int c = kt * 32 + kq + j - HD;
        float v = (myGate < 2 && c < DX) ? Wih[(size_t)row * DX + c] : 0.0f;
        f[j] = (short)f2bf(v);
      }
      bfrag[kt] = f;
    }
  } else {                               // waves 6,7: Wn fragments, K=64 pad
    const int row = 2 * HD + u0 + (wave - 6) * 16 + (lane & 15);
    for (int kt = 0; kt < 2; ++kt) {
      short8 f;
#pragma unroll
      for (int j = 0; j < 8; ++j) {
        int c = kt * 32 + kq + j;
        f[j] = (short)((c < DX) ? f2bf(Wih[(size_t)row * DX + c]) : 0);
      }
      bfrag[kt] = f;
    }
  }

  const int sb = tid >> 5;               // owned/staged h row
  const int su = tid & 31;
  const int cb = tid & 31;               // staging column block (16 units)
  float hprev = 0.0f, ssum = 0.0f, ssq = 0.0f;
  const float b_r  = bih[u0 + su] + bhh[u0 + su];
  const float b_z  = bih[HD + u0 + su] + bhh[HD + u0 + su];
  const float b_in = bih[2 * HD + u0 + su];
  const float b_hn = bhh[2 * HD + u0 + su];

  unsigned* gflags = flags + g * 128 * 16;            // 64B-strided wave flags
  unsigned* myflag = gflags + (wg * 8 + wave) * 16;
  unsigned* pollflag = gflags + (((cb >> 1) * 8) + (sb >> 1)) * 16;

  for (int t = 0; t < SEQ; ++t) {
    const ull* hin64 = (const ull*)(hbuf + ((size_t)g * 2 + (t & 1)) * MB * HD);
    uint32_t* hout32 =
        (uint32_t*)(hbuf + ((size_t)g * 2 + ((t + 1) & 1)) * MB * HD);

    // x prefetch (issues before the poll; drained before use below)
    const float* xr = x + ((size_t)(bg + sb) * SEQ + t) * DX;
    float xv0 = xr[su];
    float xv1 = (su < 8) ? xr[32 + su] : 0.0f;

    {  // fused poll + stage: one producer (cb>>1, sb>>1) per thread
      int spin = 0;
      while (__hip_atomic_load(pollflag, __ATOMIC_RELAXED,
                               __HIP_MEMORY_SCOPE_AGENT) < (unsigned)t)
        if (++spin > 2) __builtin_amdgcn_s_sleep(1);
      ull w0 = __hip_atomic_load(hin64 + sb * 128 + cb * 4 + 0, __ATOMIC_RELAXED,
                                 __HIP_MEMORY_SCOPE_AGENT);
      ull w1 = __hip_atomic_load(hin64 + sb * 128 + cb * 4 + 1, __ATOMIC_RELAXED,
                                 __HIP_MEMORY_SCOPE_AGENT);
      ull w2 = __hip_atomic_load(hin64 + sb * 128 + cb * 4 + 2, __ATOMIC_RELAXED,
                                 __HIP_MEMORY_SCOPE_AGENT);
      ull w3 = __hip_atomic_load(hin64 + sb * 128 + cb * 4 + 3, __ATOMIC_RELAXED,
                                 __HIP_MEMORY_SCOPE_AGENT);
      *(ull*)(&h_s[sb][cb * 16 + 0])  = w0;
      *(ull*)(&h_s[sb][cb * 16 + 4])  = w1;
      *(ull*)(&h_s[sb][cb * 16 + 8])  = w2;
      *(ull*)(&h_s[sb][cb * 16 + 12]) = w3;
    }
    x_s[sb][su] = f2bf(xv0);
    if (su < 8) x_s[sb][32 + su] = f2bf(xv1);
    __syncthreads();  // B: h_s/x_s staged; orders gate_s reuse across steps

    if (wave < 6) {
      const int m = lane & 15;
      f32x4 acc = {0.f, 0.f, 0.f, 0.f};
#pragma unroll
      for (int kt = 0; kt < 16; ++kt) {
        short8 av = *(const short8*)(&h_s[m][kt * 32 + kq]);
        acc = __builtin_amdgcn_mfma_f32_16x16x32_bf16(av, bfrag[kt], acc, 0, 0, 0);
      }
      short8 ax0 = *(const short8*)(&x_s[m][kq]);
      short8 ax1 = *(const short8*)(&x_s[m][32 + kq]);
      acc = __builtin_amdgcn_mfma_f32_16x16x32_bf16(ax0, bfrag[16], acc, 0, 0, 0);
      acc = __builtin_amdgcn_mfma_f32_16x16x32_bf16(ax1, bfrag[17], acc, 0, 0, 0);
#pragma unroll
      for (int r = 0; r < 4; ++r)          // C/D: col=lane&15, row=(lane>>4)*4+r
        gate_s[myGate][(lane >> 4) * 4 + r][ut * 16 + (lane & 15)] = acc[r];
    } else {                               // xn via MFMA
      const int m = lane & 15;
      f32x4 acc = {0.f, 0.f, 0.f, 0.f};
      short8 ax0 = *(const short8*)(&x_s[m][kq]);
      short8 ax1 = *(const short8*)(&x_s[m][32 + kq]);
      acc = __builtin_amdgcn_mfma_f32_16x16x32_bf16(ax0, bfrag[0], acc, 0, 0, 0);
      acc = __builtin_amdgcn_mfma_f32_16x16x32_bf16(ax1, bfrag[1], acc, 0, 0, 0);
#pragma unroll
      for (int r = 0; r < 4; ++r)
        xn_s[(lane >> 4) * 4 + r][(wave - 6) * 16 + (lane & 15)] = acc[r];
    }
    __syncthreads();  // C: gates/xn ready; h_s reads done before next stage

    float r_ = sigm(gate_s[0][sb][su] + b_r);
    float z_ = sigm(gate_s[1][sb][su] + b_z);
    float n_ = tanhf(xn_s[sb][su] + b_in + r_ * (gate_s[2][sb][su] + b_hn));
    float h = (1.0f - z_) * n_ + z_ * hprev;
    hprev = h;
    ssum += h; ssq += h * h;
    {  // per-wave release: pack bf16x2, even lanes 4B store, wave-local drain
      float hp = __shfl_xor(h, 1);
      if ((tid & 1) == 0) {
        uint32_t packed = (uint32_t)f2bf(h) | ((uint32_t)f2bf(hp) << 16);
        __hip_atomic_store(hout32 + ((sb * HD + u0 + su) >> 1), packed,
                           __ATOMIC_RELAXED, __HIP_MEMORY_SCOPE_AGENT);
      }
      asm volatile("s_waitcnt vmcnt(0)" ::: "memory");   // wave stores at LLC
      if (lane == 0)
        __hip_atomic_store(myflag, (unsigned)(t + 1), __ATOMIC_RELAXED,
                           __HIP_MEMORY_SCOPE_AGENT);
    }
    o1[((size_t)(bg + sb) * SEQ + t) * HD + u0 + su] = h;  // after publish
  }

  atomicAdd(&stats[u0 + su], ssum);
  atomicAdd(&stats[HD + u0 + su], ssq);
}

// ---------------- LSTM persistent kernel ----------------
// 8 MFMA waves (i,f,g,o x 2 unit tiles); x(40)+ssr(1) folded into K-tiles 16,17.
__global__ __launch_bounds__(512, 2) void lstm_kernel(
    const float* __restrict__ x, const float* __restrict__ Wih,
    const float* __restrict__ Whh, const float* __restrict__ bih,
    const float* __restrict__ bhh, const float* __restrict__ ssr,
    unsigned* __restrict__ flags, unsigned short* __restrict__ hbuf,
    float* __restrict__ o2)
{
  const int wg = blockIdx.x & (GW - 1);
  const int g  = blockIdx.x >> 4;
  const int tid = threadIdx.x;
  const int wave = tid >> 6;
  const int lane = tid & 63;
  const int u0 = wg * NU;
  const int bg = g * MB;

  __shared__ __attribute__((aligned(16))) unsigned short h_s[MB][520];
  __shared__ __attribute__((aligned(16))) unsigned short x_s[MB][72];
  __shared__ float gate_s[4][MB][NU];

  for (int i = tid; i < MB * 23; i += 512) x_s[i / 23][41 + (i % 23)] = 0;

  short8 bfrag[18];
  const int myGate = wave >> 1;
  const int ut = wave & 1;
  const int kq = (lane >> 4) * 8;
  {
    const int row = myGate * HD + u0 + ut * 16 + (lane & 15);
    for (int kt = 0; kt < 16; ++kt) {
      const float* p = Whh + (size_t)row * HD + kt * 32 + kq;
      short8 f;
#pragma unroll
      for (int j = 0; j < 8; ++j) f[j] = (short)f2bf(p[j]);
      bfrag[kt] = f;
    }
    for (int kt = 16; kt < 18; ++kt) {     // Wih has 41 cols (x 0..39, ssr 40)
      short8 f;
#pragma unroll
      for (int j = 0; j < 8; ++j) {
        int c = kt * 32 + kq + j - HD;
        float v = (c < 41) ? Wih[(size_t)row * 41 + c] : 0.0f;
        f[j] = (short)f2bf(v);
      }
      bfrag[kt] = f;
    }
  }

  const int sb = tid >> 5;
  const int su = tid & 31;
  const int cb = tid & 31;
  float creg = 0.0f;
  const float b_i = bih[u0 + su] + bhh[u0 + su];
  const float b_f = bih[HD + u0 + su] + bhh[HD + u0 + su];
  const float b_g = bih[2 * HD + u0 + su] + bhh[2 * HD + u0 + su];
  const float b_o = bih[3 * HD + u0 + su] + bhh[3 * HD + u0 + su];

  unsigned* gflags = flags + g * 128 * 16;
  unsigned* myflag = gflags + (wg * 8 + wave) * 16;
  unsigned* pollflag = gflags + (((cb >> 1) * 8) + (sb >> 1)) * 16;

  for (int t = 0; t < SEQ; ++t) {
    const ull* hin64 = (const ull*)(hbuf + ((size_t)g * 2 + (t & 1)) * MB * HD);
    uint32_t* hout32 =
        (uint32_t*)(hbuf + ((size_t)g * 2 + ((t + 1) & 1)) * MB * HD);

    const float* xr = x + ((size_t)(bg + sb) * SEQ + t) * DX;
    float xv0 = xr[su];
    float xv1 = (su < 8) ? xr[32 + su] : 0.0f;
    float sv = (su == 8) ? ssr[(size_t)(bg + sb) * SEQ + t] : 0.0f;

    {
      int spin = 0;
      while (__hip_atomic_load(pollflag, __ATOMIC_RELAXED,
                               __HIP_MEMORY_SCOPE_AGENT) < (unsigned)t)
        if (++spin > 2) __builtin_amdgcn_s_sleep(1);
      ull w0 = __hip_atomic_load(hin64 + sb * 128 + cb * 4 + 0, __ATOMIC_RELAXED,
                                 __HIP_MEMORY_SCOPE_AGENT);
      ull w1 = __hip_atomic_load(hin64 + sb * 128 + cb * 4 + 1, __ATOMIC_RELAXED,
                                 __HIP_MEMORY_SCOPE_AGENT);
      ull w2 = __hip_atomic_load(hin64 + sb * 128 + cb * 4 + 2, __ATOMIC_RELAXED,
                                 __HIP_MEMORY_SCOPE_AGENT);
      ull w3 = __hip_atomic_load(hin64 + sb * 128 + cb * 4 + 3, __ATOMIC_RELAXED,
                                 __HIP_MEMORY_SCOPE_AGENT);
      *(ull*)(&h_s[sb][cb * 16 + 0])  = w0;
      *(ull*)(&h_s[sb][cb * 16 + 4])  = w1;
      *(ull*)(&h_s[sb][cb * 16 + 8])  = w2;
      *(ull*)(&h_s[sb][cb * 16 + 12]) = w3;
    }
    x_s[sb][su] = f2bf(xv0);
    if (su < 8) x_s[sb][32 + su] = f2bf(xv1);
    if (su == 8) x_s[sb][40] = f2bf(sv);
    __syncthreads();  // B

    {
      const int m = lane & 15;
      f32x4 acc = {0.f, 0.f, 0.f, 0.f};
#pragma unroll
      for (int kt = 0; kt < 16; ++kt) {
        short8 av = *(const short8*)(&h_s[m][kt * 32 + kq]);
        acc = __builtin_amdgcn_mfma_f32_16x16x32_bf16(av, bfrag[kt], acc, 0, 0, 0);
      }
      short8 ax0 = *(const short8*)(&x_s[m][kq]);
      short8 ax1 = *(const short8*)(&x_s[m][32 + kq]);
      acc = __builtin_amdgcn_mfma_f32_16x16x32_bf16(ax0, bfrag[16], acc, 0, 0, 0);
      acc = __builtin_amdgcn_mfma_f32_16x16x32_bf16(ax1, bfrag[17], acc, 0, 0, 0);
#pragma unroll
      for (int r = 0; r < 4; ++r)
        gate_s[myGate][(lane >> 4) * 4 + r][ut * 16 + (lane & 15)] = acc[r];
    }
    __syncthreads();  // C

    float gi = sigm(gate_s[0][sb][su] + b_i);
    float gf_ = sigm(gate_s[1][sb][su] + b_f);
    float gg = tanhf(gate_s[2][sb][su] + b_g);
    float go = sigm(gate_s[3][sb][su] + b_o);
    creg = gf_ * creg + gi * gg;
    float h = go * tanhf(creg);
    {
      float hp = __shfl_xor(h, 1);
      if ((tid & 1) == 0) {
        uint32_t packed = (uint32_t)f2bf(h) | ((uint32_t)f2bf(hp) << 16);
        __hip_atomic_store(hout32 + ((sb * HD + u0 + su) >> 1), packed,
                           __ATOMIC_RELAXED, __HIP_MEMORY_SCOPE_AGENT);
      }
      asm volatile("s_waitcnt vmcnt(0)" ::: "memory");
      if (lane == 0)
        __hip_atomic_store(myflag, (unsigned)(t + 1), __ATOMIC_RELAXED,
                           __HIP_MEMORY_SCOPE_AGENT);
    }
    o2[((size_t)(bg + sb) * SEQ + t) * HD + u0 + su] = h;
  }
}

// ---------------- BN-coefficient kernel (1 block) ----------------
__global__ __launch_bounds__(512) void coef_kernel(
    const float* __restrict__ stats, const float* __restrict__ fc1_w,
    const float* __restrict__ fc1_b, const float* __restrict__ fc2_w,
    const float* __restrict__ fc2_b, const float* __restrict__ gamma,
    const float* __restrict__ beta, float* __restrict__ coef)
{
  __shared__ float r1[512], r2[512];
  const int j = threadIdx.x;
  const float inv_n = 1.0f / 32768.0f;
  float mean = stats[j] * inv_n;
  float var = stats[HD + j] * inv_n - mean * mean;
  float scale = gamma[j] * rsqrtf(var + 1e-5f);
  float shift = beta[j] - mean * scale;
  coef[j] = fc1_w[j] * scale;
  coef[HD + j] = fc2_w[j] * scale;
  r1[j] = fc1_w[j] * shift;
  r2[j] = fc2_w[j] * shift;
  __syncthreads();
  for (int s = 256; s > 0; s >>= 1) {
    if (j < s) { r1[j] += r1[j + s]; r2[j] += r2[j + s]; }
    __syncthreads();
  }
  if (j == 0) {
    coef[2 * HD] = r1[0] + fc1_b[0];
    coef[2 * HD + 1] = r2[0] + fc2_b[0];
  }
}

// ---------------- ssr kernel: one wave per (b,t) row ----------------
__global__ __launch_bounds__(256) void ssr_kernel(
    const float* __restrict__ o1, const float* __restrict__ coef,
    float* __restrict__ ssr_ws, float* __restrict__ dssr)
{
  const int row = blockIdx.x * 4 + (threadIdx.x >> 6);
  const int lane = threadIdx.x & 63;
  const float* p = o1 + (size_t)row * HD + lane * 8;
  float s1 = 0.f, s2 = 0.f;
#pragma unroll
  for (int j = 0; j < 8; ++j) {
    float v = p[j];
    s1 += v * coef[lane * 8 + j];
    s2 += v * coef[HD + lane * 8 + j];
  }
#pragma unroll
  for (int off = 32; off > 0; off >>= 1) {
    s1 += __shfl_down(s1, off);
    s2 += __shfl_down(s2, off);
  }
  if (lane == 0) {
    float sr = fmaxf(s1 + coef[2 * HD], 0.0f);
    float w = fabsf(sigm(s2 + coef[2 * HD + 1]));
    float v = sr * (1.0f + w);
    ssr_ws[row] = v;
    dssr[row] = v;
  }
}

// ---------------- fc3 output kernel ----------------
__global__ __launch_bounds__(256) void out_kernel(
    const float* __restrict__ o2, const float* __restrict__ fc3_w,
    const float* __restrict__ fc3_b, float* __restrict__ dout)
{
  const int row = blockIdx.x * 4 + (threadIdx.x >> 6);
  const int lane = threadIdx.x & 63;
  const float* p = o2 + (size_t)row * HD + lane * 8;
  float s = 0.f;
#pragma unroll
  for (int j = 0; j < 8; ++j) s += p[j] * fc3_w[lane * 8 + j];
#pragma unroll
  for (int off = 32; off > 0; off >>= 1) s += __shfl_down(s, off);
  if (lane == 0) dout[row] = fmaxf(s + fc3_b[0], 0.0f);
}

extern "C" void kernel_launch(void* const* d_in, const int* in_sizes, int n_in,
                              void* d_out, int out_size, void* d_ws, size_t ws_size,
                              hipStream_t stream) {
  (void)in_sizes; (void)n_in; (void)out_size; (void)ws_size;
  const float* x    = (const float*)d_in[0];
  const float* gWih = (const float*)d_in[1];
  const float* gWhh = (const float*)d_in[2];
  const float* gbih = (const float*)d_in[3];
  const float* gbhh = (const float*)d_in[4];
  const float* lWih = (const float*)d_in[5];
  const float* lWhh = (const float*)d_in[6];
  const float* lbih = (const float*)d_in[7];
  const float* lbhh = (const float*)d_in[8];
  const float* fc1w = (const float*)d_in[9];
  const float* fc1b = (const float*)d_in[10];
  const float* fc2w = (const float*)d_in[11];
  const float* fc2b = (const float*)d_in[12];
  const float* fc3w = (const float*)d_in[13];
  const float* fc3b = (const float*)d_in[14];
  const float* gam  = (const float*)d_in[15];
  const float* bet  = (const float*)d_in[16];
  float* out = (float*)d_out;

  char* ws = (char*)d_ws;
  unsigned* flags_g = (unsigned*)(ws + 0);            // 4 g x 128 waves x 64B
  unsigned* flags_l = (unsigned*)(ws + 32768);
  float* stats      = (float*)(ws + 65536);           // 1024 f32
  float* coef       = (float*)(ws + 73728);           // 1026 f32
  float* ssr_ws     = (float*)(ws + 81920);           // 32768 f32
  unsigned short* hbuf_g = (unsigned short*)(ws + 262144);   // 128KB
  unsigned short* hbuf_l = (unsigned short*)(ws + 393216);   // 128KB
  float* o1 = (float*)(ws + 1048576);                 // 64MB
  float* o2 = o1 + (size_t)64 * SEQ * HD;             // 64MB

  hipMemsetAsync(ws, 0, 69632, stream);               // flags + stats
  hipMemsetAsync(ws + 262144, 0, 262144, stream);     // h exchange (h0=0)

  gru_kernel<<<dim3(64), dim3(512), 0, stream>>>(x, gWih, gWhh, gbih, gbhh,
                                                 flags_g, hbuf_g, o1, stats);
  coef_kernel<<<dim3(1), dim3(512), 0, stream>>>(stats, fc1w, fc1b, fc2w, fc2b,
                                                 gam, bet, coef);
  ssr_kernel<<<dim3(8192), dim3(256), 0, stream>>>(o1, coef, ssr_ws, out + 32768);
  lstm_kernel<<<dim3(64), dim3(512), 0, stream>>>(x, lWih, lWhh, lbih, lbhh, ssr_ws,
                                                  flags_l, hbuf_l, o2);
  out_kernel<<<dim3(8192), dim3(256), 0, stream>>>(o2, fc3w, fc3b, out);
}